// Round 5
// baseline (195.493 us; speedup 1.0000x reference)
//
#include <hip/hip_runtime.h>
#include <math.h>

#define B_ 4
#define N_ 16384
#define M_ 1024
#define C_ 64

// output layout (floats): new_xyz [B*M*3] | feats [B*256*M] | inds [B*M]
#define OUT_XYZ_ELEMS (B_ * M_ * 3)
#define OUT_FEAT_ELEMS (B_ * 256 * M_)
#define PST 1024  // partial-stats stride (>= max j-blocks)

typedef __attribute__((ext_vector_type(8))) short bf16x8;
typedef __attribute__((ext_vector_type(4))) float f32x4;

__device__ __forceinline__ unsigned short f2bf(float f) {
    unsigned int u = __float_as_uint(f);
    u += 0x7fffu + ((u >> 16) & 1u);
    return (unsigned short)(u >> 16);
}
__device__ __forceinline__ float bf2f(unsigned short h) {
    return __uint_as_float(((unsigned int)h) << 16);
}

struct MMP {
    const float* W;
    const unsigned short* Xp;
    const float* ssin;
    unsigned short* Yp;
    float* Ymax;
    float* pS;
    float* pS2;
    const unsigned short* featsT;
    const int* idxb;
    const ushort4* relb;
    int cin, Nj, nslog, nspool, jb_log;
};

// ------------------------------------------------------------------
// prep: blocks [0,1024) transpose feats (B,C,N)f32 -> featsT (B,N,64)bf16;
// blocks [1024,2048) dual-radius ball query (one wave/query) + center gather.
// Ball also emits bf16 rel-xyz per neighbor (shfl from testing lane).
__global__ __launch_bounds__(256) void k_prep(const float* __restrict__ xyz,
                                              const float* __restrict__ feats,
                                              const int* __restrict__ inds,
                                              unsigned short* __restrict__ featsT,
                                              float* __restrict__ out,
                                              int* __restrict__ idx0, ushort4* __restrict__ rel0,
                                              int* __restrict__ idx1, ushort4* __restrict__ rel1,
                                              float r0sq, float r1sq) {
    __shared__ unsigned short T[64][72];
    int bx = blockIdx.x;
    if (bx < 1024) {
        int b = bx >> 8;
        int n0 = (bx & 255) << 6;
        int tn = threadIdx.x & 63;
        int c0 = threadIdx.x >> 6;
        const float* fp = feats + (size_t)b * C_ * N_ + n0 + tn;
        #pragma unroll
        for (int it = 0; it < 16; ++it) {
            int c = it * 4 + c0;
            T[c][tn] = f2bf(fp[(size_t)c * N_]);
        }
        __syncthreads();
        for (int s = threadIdx.x; s < 64 * 8; s += 256) {
            int n = s >> 3, ch = s & 7;
            unsigned int pk[4];
            #pragma unroll
            for (int e = 0; e < 4; ++e)
                pk[e] = (unsigned int)T[ch * 8 + e * 2][n] | ((unsigned int)T[ch * 8 + e * 2 + 1][n] << 16);
            *(uint4*)&featsT[(((size_t)b * N_ + n0 + n) << 6) + ch * 8] =
                make_uint4(pk[0], pk[1], pk[2], pk[3]);
        }
        return;
    }
    // ---- ball region ----
    int lane = threadIdx.x & 63;
    int t = (bx - 1024) * 4 + (threadIdx.x >> 6);
    int b = t >> 10;
    int n0 = inds[t];
    const float* bp = xyz + (size_t)b * N_ * 3;
    float qx = bp[n0 * 3 + 0], qy = bp[n0 * 3 + 1], qz = bp[n0 * 3 + 2];
    if (lane == 0) {
        out[t * 3 + 0] = qx;
        out[t * 3 + 1] = qy;
        out[t * 3 + 2] = qz;
        out[OUT_XYZ_ELEMS + OUT_FEAT_ELEMS + t] = (float)n0;
    }
    int cnt0 = 0, cnt1 = 0, first0 = n0, first1 = n0;
    ushort4 rf0 = make_ushort4(0, 0, 0, 0), rf1 = make_ushort4(0, 0, 0, 0);
    for (int base = 0; base < N_ && (cnt0 < 16 || cnt1 < 32); base += 64) {
        int n = base + lane;
        float dx = __fsub_rn(bp[n * 3 + 0], qx);
        float dy = __fsub_rn(bp[n * 3 + 1], qy);
        float dz = __fsub_rn(bp[n * 3 + 2], qz);
        float d2 = __fadd_rn(__fadd_rn(__fmul_rn(dx, dx), __fmul_rn(dy, dy)), __fmul_rn(dz, dz));
        unsigned long long m1 = __ballot(d2 < r1sq);
        unsigned long long m0 = __ballot(d2 < r0sq);
        while (m1) {
            int bit = (int)__builtin_ctzll(m1);
            m1 &= m1 - 1;
            int nn = base + bit;
            float sx = __shfl(dx, bit), sy = __shfl(dy, bit), sz = __shfl(dz, bit);
            ushort4 r = make_ushort4(f2bf(sx), f2bf(sy), f2bf(sz), 0);
            if (cnt1 < 32) {
                if (cnt1 == 0) { first1 = nn; rf1 = r; }
                if (lane == 0) { idx1[t * 32 + cnt1] = nn; rel1[t * 32 + cnt1] = r; }
                cnt1++;
            }
            if (cnt0 < 16 && ((m0 >> bit) & 1ull)) {
                if (cnt0 == 0) { first0 = nn; rf0 = r; }
                if (lane == 0) { idx0[t * 16 + cnt0] = nn; rel0[t * 16 + cnt0] = r; }
                cnt0++;
            }
            if (cnt1 >= 32 && cnt0 >= 16) break;
        }
    }
    if (lane == 0) {
        for (int k2 = cnt0; k2 < 16; ++k2) { idx0[t * 16 + k2] = first0; rel0[t * 16 + k2] = rf0; }
        for (int k2 = cnt1; k2 < 32; ++k2) { idx1[t * 32 + k2] = first1; rel1[t * 32 + k2] = rf1; }
    }
}

// ------------------------------------------------------------------
// MFMA GEMM, dual-scale via param structs: block bx < split -> p0 else p1.
// GATHER: B-fragments gathered from featsT (channels permuted: 0..63 feats,
//   64..66 rel-xyz (precomputed bf16), pad 96; W rows permuted to match).
// else: Xp[c>>3][j][c&7] packed bf16; BN? x=relu(sc*X+sh) (guarded c<cin).
// POOL: fused max-pool over runtime nspool (16/32) -> Ymax[bm][o]; else bf16 Yp.
// Always: per-block per-channel partial stats to pS/pS2.
template <int KB, int OT, int TPW, bool BN, bool GATHER, bool POOL>
__global__ __launch_bounds__(256) void k_mm(MMP p0, MMP p1, int split) {
    __shared__ unsigned short Wa[KB * OT * 512];
    __shared__ float sm1[4][OT * 16];
    __shared__ float sm2[4][OT * 16];
    int bx = blockIdx.x;
    const bool sel = bx >= split;
    const MMP P = sel ? p1 : p0;
    if (sel) bx -= split;
    const int oy = bx >> P.jb_log;
    const int jx = bx & ((1 << P.jb_log) - 1);
    const int tid = threadIdx.x;
    const int lane = tid & 63;
    const int wid = tid >> 6;
    const int q = lane >> 4;
    const int jl = lane & 15;
    const int oybase = oy * OT * 16;

    // stage A-fragments (zero-pad c >= cin)
    for (int s = tid; s < KB * OT * 64; s += 256) {
        int kb = s / (OT * 64);
        int r = s - kb * (OT * 64);
        int ot = r >> 6;
        int sl = r & 63;
        int o = oybase + ot * 16 + (sl & 15);
        int cbase = kb * 32 + (sl >> 4) * 8;
        unsigned int pk[4];
        #pragma unroll
        for (int e2 = 0; e2 < 4; ++e2) {
            int c0 = cbase + e2 * 2, c1 = c0 + 1;
            unsigned short lo, hi;
            if (GATHER) {
                lo = (c0 < 64) ? f2bf(P.W[(size_t)o * 67 + 3 + c0])
                               : (c0 < 67 ? f2bf(P.W[(size_t)o * 67 + c0 - 64]) : (unsigned short)0);
                hi = (c1 < 64) ? f2bf(P.W[(size_t)o * 67 + 3 + c1])
                               : (c1 < 67 ? f2bf(P.W[(size_t)o * 67 + c1 - 64]) : (unsigned short)0);
            } else {
                lo = (c0 < P.cin) ? f2bf(P.W[(size_t)o * P.cin + c0]) : (unsigned short)0;
                hi = (c1 < P.cin) ? f2bf(P.W[(size_t)o * P.cin + c1]) : (unsigned short)0;
            }
            pk[e2] = (unsigned int)lo | ((unsigned int)hi << 16);
        }
        *(uint4*)&Wa[(size_t)s * 8] = make_uint4(pk[0], pk[1], pk[2], pk[3]);
    }
    __syncthreads();

    bf16x8 a[KB][OT];
    #pragma unroll
    for (int kb = 0; kb < KB; ++kb)
        #pragma unroll
        for (int ot = 0; ot < OT; ++ot)
            a[kb][ot] = *(const bf16x8*)&Wa[((kb * OT + ot) * 64 + lane) * 8];

    float sc[KB][8], sh[KB][8];
    if (BN) {
        #pragma unroll
        for (int kb = 0; kb < KB; ++kb)
            #pragma unroll
            for (int e = 0; e < 8; ++e) {
                int c = kb * 32 + q * 8 + e;
                bool ok = c < P.cin;
                sc[kb][e] = ok ? P.ssin[c * 2 + 0] : 0.f;
                sh[kb][e] = ok ? P.ssin[c * 2 + 1] : 0.f;
            }
    }

    float s1_[OT][4], s2_[OT][4], rmax[OT][4];
    #pragma unroll
    for (int ot = 0; ot < OT; ++ot)
        #pragma unroll
        for (int r = 0; r < 4; ++r) { s1_[ot][r] = 0.f; s2_[ot][r] = 0.f; rmax[ot][r] = 0.f; }

    const int wtile0 = (jx * 4 + wid) * TPW;
    #pragma unroll
    for (int i = 0; i < TPW; ++i) {
        const int t = wtile0 + i;
        const int jj = t * 16 + jl;
        f32x4 acc[OT];
        #pragma unroll
        for (int ot = 0; ot < OT; ++ot) acc[ot] = (f32x4){0.f, 0.f, 0.f, 0.f};

        const unsigned short* fr_row = nullptr;
        ushort4 rl = make_ushort4(0, 0, 0, 0);
        if (GATHER) {
            int nidx = P.idxb[jj];
            int bm = jj >> P.nslog;
            int b = bm >> 10;
            fr_row = P.featsT + (((size_t)b * N_ + nidx) << 6);
            rl = P.relb[jj];
        }

        #pragma unroll
        for (int kb = 0; kb < KB; ++kb) {
            bf16x8 bf;
            if (GATHER) {
                if (kb < 2) {
                    bf = *(const bf16x8*)&fr_row[kb * 32 + q * 8];
                } else {
                    bf = (bf16x8){0, 0, 0, 0, 0, 0, 0, 0};
                    if (q == 0) {
                        bf[0] = (short)rl.x;
                        bf[1] = (short)rl.y;
                        bf[2] = (short)rl.z;
                    }
                }
            } else {
                bf = *(const bf16x8*)&P.Xp[((size_t)(kb * 4 + q) * P.Nj + jj) * 8];
                if (BN) {
                    bf16x8 nb;
                    #pragma unroll
                    for (int e = 0; e < 8; ++e) {
                        float x = bf2f((unsigned short)bf[e]);
                        float z = fmaxf(fmaf(x, sc[kb][e], sh[kb][e]), 0.f);
                        nb[e] = (short)f2bf(z);
                    }
                    bf = nb;
                }
            }
            #pragma unroll
            for (int ot = 0; ot < OT; ++ot)
                acc[ot] = __builtin_amdgcn_mfma_f32_16x16x32_bf16(a[kb][ot], bf, acc[ot], 0, 0, 0);
        }

        #pragma unroll
        for (int ot = 0; ot < OT; ++ot)
            #pragma unroll
            for (int r = 0; r < 4; ++r) {
                float v = acc[ot][r];
                s1_[ot][r] += v;
                s2_[ot][r] = fmaf(v, v, s2_[ot][r]);
            }

        if (!POOL) {
            #pragma unroll
            for (int ot = 0; ot < OT; ++ot) {
                int o0 = oybase + ot * 16 + q * 4;
                unsigned int lo = (unsigned int)f2bf(acc[ot][0]) | ((unsigned int)f2bf(acc[ot][1]) << 16);
                unsigned int hi = (unsigned int)f2bf(acc[ot][2]) | ((unsigned int)f2bf(acc[ot][3]) << 16);
                *(uint2*)&P.Yp[((size_t)(o0 >> 3) * P.Nj + jj) * 8 + (o0 & 7)] = make_uint2(lo, hi);
            }
        } else {
            bool flush = (P.nspool == 16) || ((i & 1) == 1);
            if (flush) {
                float mm[OT][4];
                #pragma unroll
                for (int ot = 0; ot < OT; ++ot)
                    #pragma unroll
                    for (int r = 0; r < 4; ++r)
                        mm[ot][r] = (P.nspool == 32) ? fmaxf(rmax[ot][r], acc[ot][r]) : acc[ot][r];
                #pragma unroll
                for (int ot = 0; ot < OT; ++ot)
                    #pragma unroll
                    for (int r = 0; r < 4; ++r) {
                        float v = mm[ot][r];
                        v = fmaxf(v, __shfl_xor(v, 1));
                        v = fmaxf(v, __shfl_xor(v, 2));
                        v = fmaxf(v, __shfl_xor(v, 4));
                        v = fmaxf(v, __shfl_xor(v, 8));
                        mm[ot][r] = v;
                    }
                if (jl == 0) {
                    int bm = (P.nspool == 32) ? (t >> 1) : t;
                    #pragma unroll
                    for (int ot = 0; ot < OT; ++ot)
                        *(float4*)&P.Ymax[(size_t)bm * 128 + oybase + ot * 16 + q * 4] =
                            make_float4(mm[ot][0], mm[ot][1], mm[ot][2], mm[ot][3]);
                }
            } else {
                #pragma unroll
                for (int ot = 0; ot < OT; ++ot)
                    #pragma unroll
                    for (int r = 0; r < 4; ++r) rmax[ot][r] = acc[ot][r];
            }
        }
    }

    // per-block channel partials
    #pragma unroll
    for (int ot = 0; ot < OT; ++ot)
        #pragma unroll
        for (int r = 0; r < 4; ++r) {
            float v1 = s1_[ot][r], v2 = s2_[ot][r];
            v1 += __shfl_xor(v1, 1); v2 += __shfl_xor(v2, 1);
            v1 += __shfl_xor(v1, 2); v2 += __shfl_xor(v2, 2);
            v1 += __shfl_xor(v1, 4); v2 += __shfl_xor(v2, 4);
            v1 += __shfl_xor(v1, 8); v2 += __shfl_xor(v2, 8);
            s1_[ot][r] = v1; s2_[ot][r] = v2;
        }
    if (jl == 0) {
        #pragma unroll
        for (int ot = 0; ot < OT; ++ot)
            #pragma unroll
            for (int r = 0; r < 4; ++r) {
                sm1[wid][ot * 16 + q * 4 + r] = s1_[ot][r];
                sm2[wid][ot * 16 + q * 4 + r] = s2_[ot][r];
            }
    }
    __syncthreads();
    for (int o = tid; o < OT * 16; o += 256) {
        float a1 = sm1[0][o] + sm1[1][o] + sm1[2][o] + sm1[3][o];
        float a2 = sm2[0][o] + sm2[1][o] + sm2[2][o] + sm2[3][o];
        P.pS[(size_t)(oybase + o) * PST + jx] = a1;
        P.pS2[(size_t)(oybase + o) * PST + jx] = a2;
    }
}

// ------------------------------------------------------------------
// merged fin: blocks [0,ca) scale0 channels, [ca, ca+cb) scale1 channels
__global__ __launch_bounds__(64) void k_fin2(const float* __restrict__ pSa, const float* __restrict__ pS2a,
                                             const float* __restrict__ ga, const float* __restrict__ ba,
                                             float* __restrict__ ssa, int ca, int gxa, float invNa,
                                             const float* __restrict__ pSb, const float* __restrict__ pS2b,
                                             const float* __restrict__ gb, const float* __restrict__ bbv,
                                             float* __restrict__ ssb, int gxb, float invNb) {
    int o = blockIdx.x;
    const float *pS, *pS2, *g, *bt;
    float* ss;
    int gx;
    float invN;
    if (o < ca) { pS = pSa; pS2 = pS2a; g = ga; bt = ba; ss = ssa; gx = gxa; invN = invNa; }
    else { o -= ca; pS = pSb; pS2 = pS2b; g = gb; bt = bbv; ss = ssb; gx = gxb; invN = invNb; }
    int l = threadIdx.x;
    float s = 0.f, s2 = 0.f;
    for (int i = l; i < gx; i += 64) {
        s += pS[(size_t)o * PST + i];
        s2 += pS2[(size_t)o * PST + i];
    }
    #pragma unroll
    for (int off = 1; off < 64; off <<= 1) {
        s += __shfl_xor(s, off, 64);
        s2 += __shfl_xor(s2, off, 64);
    }
    if (l == 0) {
        float mean = s * invN;
        float var = s2 * invN - mean * mean;
        float scale = g[o] / sqrtf(var + 1e-5f);
        float shift = bt[o] - mean * scale;
        ss[o * 2 + 0] = scale;
        ss[o * 2 + 1] = shift;
    }
}

// ------------------------------------------------------------------
// merged poolfin: blocks [0,64) scale0, [64,128) scale1
__global__ __launch_bounds__(256) void k_poolfin2(const float* __restrict__ Ymax0, const float* __restrict__ ss0,
                                                  const float* __restrict__ Ymax1, const float* __restrict__ ss1,
                                                  float* __restrict__ out) {
    __shared__ float T[128][65];
    int blk = blockIdx.x;
    const float* Ymax;
    const float* ss;
    int o_off;
    if (blk < 64) { Ymax = Ymax0; ss = ss0; o_off = 0; }
    else { blk -= 64; Ymax = Ymax1; ss = ss1; o_off = 128; }
    int b = blk >> 4, mc = blk & 15;
    int bm0 = b * M_ + mc * 64;
    for (int s = threadIdx.x; s < 64 * 32; s += 256) {
        int row = s >> 5;
        int c4 = s & 31;
        float4 v = *(const float4*)&Ymax[(size_t)(bm0 + row) * 128 + c4 * 4];
        T[c4 * 4 + 0][row] = v.x;
        T[c4 * 4 + 1][row] = v.y;
        T[c4 * 4 + 2][row] = v.z;
        T[c4 * 4 + 3][row] = v.w;
    }
    __syncthreads();
    for (int s = threadIdx.x; s < 128 * 16; s += 256) {
        int o = s >> 4, m4 = s & 15;
        float scv = ss[o * 2 + 0], shv = ss[o * 2 + 1];
        float4 v = make_float4(T[o][m4 * 4], T[o][m4 * 4 + 1], T[o][m4 * 4 + 2], T[o][m4 * 4 + 3]);
        v.x = fmaxf(fmaf(v.x, scv, shv), 0.f);
        v.y = fmaxf(fmaf(v.y, scv, shv), 0.f);
        v.z = fmaxf(fmaf(v.z, scv, shv), 0.f);
        v.w = fmaxf(fmaf(v.w, scv, shv), 0.f);
        *(float4*)&out[OUT_XYZ_ELEMS + ((size_t)(b * 256 + o_off + o)) * M_ + mc * 64 + m4 * 4] = v;
    }
}

// ------------------------------------------------------------------
extern "C" void kernel_launch(void* const* d_in, const int* in_sizes, int n_in,
                              void* d_out, int out_size, void* d_ws, size_t ws_size,
                              hipStream_t stream) {
    const float* xyz = (const float*)d_in[0];
    const float* feats = (const float*)d_in[1];
    const int* inds = (const int*)d_in[2];
    const float* w[2][3];
    const float* gg[2][3];
    const float* bb[2][3];
    int k = 3;
    for (int i = 0; i < 2; ++i)
        for (int l = 0; l < 3; ++l) {
            w[i][l] = (const float*)d_in[k++];
            gg[i][l] = (const float*)d_in[k++];
            bb[i][l] = (const float*)d_in[k++];
        }
    float* out = (float*)d_out;

    const int Nj0 = B_ * M_ * 16;  // 65536
    const int Nj1 = B_ * M_ * 32;  // 131072

    unsigned short* featsT = (unsigned short*)d_ws;          // B*N*64
    unsigned short* bufB0 = featsT + (size_t)B_ * N_ * 64;   // 8 chunks x Nj0 x 8
    unsigned short* bufA0 = bufB0 + (size_t)8 * Nj0 * 8;     // 12 chunks x Nj0 x 8
    unsigned short* bufB1 = bufA0 + (size_t)12 * Nj0 * 8;    // 8 chunks x Nj1 x 8
    unsigned short* bufA1 = bufB1 + (size_t)8 * Nj1 * 8;     // 12 chunks x Nj1 x 8
    float* Ymax0 = (float*)(bufA1 + (size_t)12 * Nj1 * 8);   // [4096][128]
    float* Ymax1 = Ymax0 + (size_t)B_ * M_ * 128;
    float* pS0 = Ymax1 + (size_t)B_ * M_ * 128;
    float* pS2_0 = pS0 + (size_t)128 * PST;
    float* pS1 = pS2_0 + (size_t)128 * PST;
    float* pS2_1 = pS1 + (size_t)128 * PST;
    float* ss0 = pS2_1 + (size_t)128 * PST;
    float* ss1 = ss0 + 256;
    int* idx0 = (int*)(ss1 + 256);
    int* idx1 = idx0 + Nj0;
    ushort4* rel0 = (ushort4*)(idx1 + Nj1);
    ushort4* rel1 = rel0 + Nj0;

    const float inv0 = 1.f / Nj0, inv1 = 1.f / Nj1;

    // 1) prep: transpose + dual ball + center gather
    k_prep<<<2048, 256, 0, stream>>>(xyz, feats, inds, featsT, out,
                                     idx0, rel0, idx1, rel1,
                                     (float)(0.4 * 0.4), (float)(0.8 * 0.8));

    MMP z{};  // template for filling
    // 2) layer0 merged (GATHER), cout=64 both scales
    MMP a0 = z, a1 = z;
    a0.W = w[0][0]; a0.Yp = bufB0; a0.pS = pS0; a0.pS2 = pS2_0;
    a0.featsT = featsT; a0.idxb = idx0; a0.relb = rel0;
    a0.cin = 67; a0.Nj = Nj0; a0.nslog = 4; a0.jb_log = 9;
    a1 = a0;
    a1.W = w[1][0]; a1.Yp = bufB1; a1.pS = pS1; a1.pS2 = pS2_1;
    a1.idxb = idx1; a1.relb = rel1; a1.Nj = Nj1; a1.nslog = 5; a1.jb_log = 10;
    k_mm<3, 4, 2, false, true, false><<<1536, 256, 0, stream>>>(a0, a1, 512);
    k_fin2<<<128, 64, 0, stream>>>(pS0, pS2_0, gg[0][0], bb[0][0], ss0, 64, 512, inv0,
                                   pS1, pS2_1, gg[1][0], bb[1][0], ss1, 1024, inv1);

    // 3) layer1 (separate templates per scale)
    MMP b0 = z;
    b0.W = w[0][1]; b0.Xp = bufB0; b0.ssin = ss0; b0.Yp = bufA0;
    b0.pS = pS0; b0.pS2 = pS2_0; b0.cin = 64; b0.Nj = Nj0; b0.jb_log = 9;
    k_mm<2, 4, 2, true, false, false><<<512, 256, 0, stream>>>(b0, b0, 1 << 30);
    MMP b1 = z;
    b1.W = w[1][1]; b1.Xp = bufB1; b1.ssin = ss1; b1.Yp = bufA1;
    b1.pS = pS1; b1.pS2 = pS2_1; b1.cin = 64; b1.Nj = Nj1; b1.jb_log = 10;
    k_mm<2, 6, 2, true, false, false><<<1024, 256, 0, stream>>>(b1, b1, 1 << 30);
    k_fin2<<<160, 64, 0, stream>>>(pS0, pS2_0, gg[0][1], bb[0][1], ss0, 64, 512, inv0,
                                   pS1, pS2_1, gg[1][1], bb[1][1], ss1, 1024, inv1);

    // 4) layer2 merged (POOL), cout=128 both scales
    MMP c0 = z, c1 = z;
    c0.W = w[0][2]; c0.Xp = bufA0; c0.ssin = ss0; c0.Ymax = Ymax0;
    c0.pS = pS0; c0.pS2 = pS2_0; c0.cin = 64; c0.Nj = Nj0; c0.nspool = 16; c0.jb_log = 9;
    c1.W = w[1][2]; c1.Xp = bufA1; c1.ssin = ss1; c1.Ymax = Ymax1;
    c1.pS = pS1; c1.pS2 = pS2_1; c1.cin = 96; c1.Nj = Nj1; c1.nspool = 32; c1.jb_log = 10;
    k_mm<3, 4, 2, true, false, true><<<3072, 256, 0, stream>>>(c0, c1, 1024);
    k_fin2<<<256, 64, 0, stream>>>(pS0, pS2_0, gg[0][2], bb[0][2], ss0, 128, 512, inv0,
                                   pS1, pS2_1, gg[1][2], bb[1][2], ss1, 1024, inv1);

    // 5) final BN+ReLU on pooled maxima + transpose to output
    k_poolfin2<<<128, 256, 0, stream>>>(Ymax0, ss0, Ymax1, ss1, out);
}

// Round 6
// 139.779 us; speedup vs baseline: 1.3986x; 1.3986x over previous
//
#include <hip/hip_runtime.h>
#include <math.h>

#define B_ 4
#define N_ 16384
#define M_ 1024
#define C_ 64

// output layout (floats): new_xyz [B*M*3] | feats [B*256*M] | inds [B*M]
#define OUT_XYZ_ELEMS (B_ * M_ * 3)
#define OUT_FEAT_ELEMS (B_ * 256 * M_)
#define PST 1024  // partial-stats stride (>= max j-blocks)

typedef __attribute__((ext_vector_type(8))) short bf16x8;
typedef __attribute__((ext_vector_type(4))) float f32x4;

__device__ __forceinline__ unsigned short f2bf(float f) {
    unsigned int u = __float_as_uint(f);
    u += 0x7fffu + ((u >> 16) & 1u);
    return (unsigned short)(u >> 16);
}
__device__ __forceinline__ float bf2f(unsigned short h) {
    return __uint_as_float(((unsigned int)h) << 16);
}

struct MMP {
    const float* W;
    const unsigned short* Xp;
    const float* ssin;
    unsigned short* Yp;
    float* Ymax;
    float* pS;
    float* pS2;
    const unsigned short* featsT;
    const int* idxb;
    const ushort4* relb;
    int cin, Nj, nslog, nspool, jb_log;
};

// ------------------------------------------------------------------
// prep: blocks [0,1024) transpose feats (B,C,N)f32 -> featsT (B,N,64)bf16;
// blocks [1024,2048) dual-radius ball query (one wave/query) + center gather.
// Ball also emits bf16 rel-xyz per neighbor (shfl from testing lane).
__global__ __launch_bounds__(256) void k_prep(const float* __restrict__ xyz,
                                              const float* __restrict__ feats,
                                              const int* __restrict__ inds,
                                              unsigned short* __restrict__ featsT,
                                              float* __restrict__ out,
                                              int* __restrict__ idx0, ushort4* __restrict__ rel0,
                                              int* __restrict__ idx1, ushort4* __restrict__ rel1,
                                              float r0sq, float r1sq) {
    __shared__ unsigned short T[64][72];
    int bx = blockIdx.x;
    if (bx < 1024) {
        int b = bx >> 8;
        int n0 = (bx & 255) << 6;
        int tn = threadIdx.x & 63;
        int c0 = threadIdx.x >> 6;
        const float* fp = feats + (size_t)b * C_ * N_ + n0 + tn;
        #pragma unroll
        for (int it = 0; it < 16; ++it) {
            int c = it * 4 + c0;
            T[c][tn] = f2bf(fp[(size_t)c * N_]);
        }
        __syncthreads();
        for (int s = threadIdx.x; s < 64 * 8; s += 256) {
            int n = s >> 3, ch = s & 7;
            unsigned int pk[4];
            #pragma unroll
            for (int e = 0; e < 4; ++e)
                pk[e] = (unsigned int)T[ch * 8 + e * 2][n] | ((unsigned int)T[ch * 8 + e * 2 + 1][n] << 16);
            *(uint4*)&featsT[(((size_t)b * N_ + n0 + n) << 6) + ch * 8] =
                make_uint4(pk[0], pk[1], pk[2], pk[3]);
        }
        return;
    }
    // ---- ball region ----
    int lane = threadIdx.x & 63;
    int t = (bx - 1024) * 4 + (threadIdx.x >> 6);
    int b = t >> 10;
    int n0 = inds[t];
    const float* bp = xyz + (size_t)b * N_ * 3;
    float qx = bp[n0 * 3 + 0], qy = bp[n0 * 3 + 1], qz = bp[n0 * 3 + 2];
    if (lane == 0) {
        out[t * 3 + 0] = qx;
        out[t * 3 + 1] = qy;
        out[t * 3 + 2] = qz;
        out[OUT_XYZ_ELEMS + OUT_FEAT_ELEMS + t] = (float)n0;
    }
    int cnt0 = 0, cnt1 = 0, first0 = n0, first1 = n0;
    ushort4 rf0 = make_ushort4(0, 0, 0, 0), rf1 = make_ushort4(0, 0, 0, 0);
    for (int base = 0; base < N_ && (cnt0 < 16 || cnt1 < 32); base += 64) {
        int n = base + lane;
        float dx = __fsub_rn(bp[n * 3 + 0], qx);
        float dy = __fsub_rn(bp[n * 3 + 1], qy);
        float dz = __fsub_rn(bp[n * 3 + 2], qz);
        float d2 = __fadd_rn(__fadd_rn(__fmul_rn(dx, dx), __fmul_rn(dy, dy)), __fmul_rn(dz, dz));
        unsigned long long m1 = __ballot(d2 < r1sq);
        unsigned long long m0 = __ballot(d2 < r0sq);
        if (cnt1 >= 32) m1 &= m0;  // only r0 candidates still matter
        while (m1) {
            int bit = (int)__builtin_ctzll(m1);
            m1 &= m1 - 1;
            int nn = base + bit;
            float sx = __shfl(dx, bit), sy = __shfl(dy, bit), sz = __shfl(dz, bit);
            ushort4 r = make_ushort4(f2bf(sx), f2bf(sy), f2bf(sz), 0);
            if (cnt1 < 32) {
                if (cnt1 == 0) { first1 = nn; rf1 = r; }
                if (lane == 0) { idx1[t * 32 + cnt1] = nn; rel1[t * 32 + cnt1] = r; }
                cnt1++;
                if (cnt1 == 32) m1 &= m0;
            }
            if (cnt0 < 16 && ((m0 >> bit) & 1ull)) {
                if (cnt0 == 0) { first0 = nn; rf0 = r; }
                if (lane == 0) { idx0[t * 16 + cnt0] = nn; rel0[t * 16 + cnt0] = r; }
                cnt0++;
            }
            if (cnt1 >= 32 && cnt0 >= 16) break;
        }
    }
    if (lane == 0) {
        for (int k2 = cnt0; k2 < 16; ++k2) { idx0[t * 16 + k2] = first0; rel0[t * 16 + k2] = rf0; }
        for (int k2 = cnt1; k2 < 32; ++k2) { idx1[t * 32 + k2] = first1; rel1[t * 32 + k2] = rf1; }
    }
}

// ------------------------------------------------------------------
// MFMA GEMM, dual-scale via param structs: block bx < split -> p0 else p1.
// GATHER: B-fragments gathered from featsT (channels permuted: 0..63 feats,
//   64..66 rel-xyz (precomputed bf16), pad 96; W rows permuted to match).
//   Blocks XCD-swizzled so each XCD gathers one batch's featsT slice (2MB,
//   fits 4MB XCD L2): jx = (bx&7)<<(jb_log-3) | bx>>3.
// else: Xp[c>>3][j][c&7] packed bf16; BN? x=relu(sc*X+sh) (guarded c<cin).
// POOL: fused max-pool over runtime nspool (16/32) -> Ymax[bm][o]; else bf16 Yp.
// Always: per-block per-channel partial stats to pS/pS2.
template <int KB, int OT, int TPW, bool BN, bool GATHER, bool POOL>
__global__ __launch_bounds__(256) void k_mm(MMP p0, MMP p1, int split) {
    __shared__ unsigned short Wa[KB * OT * 512];
    __shared__ float sm1[4][OT * 16];
    __shared__ float sm2[4][OT * 16];
    int bx = blockIdx.x;
    const bool sel = bx >= split;
    const MMP P = sel ? p1 : p0;
    if (sel) bx -= split;
    int oy, jx;
    if (GATHER) {  // grid = 1<<jb_log blocks, cout = OT*16
        oy = 0;
        jx = ((bx & 7) << (P.jb_log - 3)) | (bx >> 3);
    } else {
        oy = bx >> P.jb_log;
        jx = bx & ((1 << P.jb_log) - 1);
    }
    const int tid = threadIdx.x;
    const int lane = tid & 63;
    const int wid = tid >> 6;
    const int q = lane >> 4;
    const int jl = lane & 15;
    const int oybase = oy * OT * 16;

    // stage A-fragments (zero-pad c >= cin)
    for (int s = tid; s < KB * OT * 64; s += 256) {
        int kb = s / (OT * 64);
        int r = s - kb * (OT * 64);
        int ot = r >> 6;
        int sl = r & 63;
        int o = oybase + ot * 16 + (sl & 15);
        int cbase = kb * 32 + (sl >> 4) * 8;
        unsigned int pk[4];
        #pragma unroll
        for (int e2 = 0; e2 < 4; ++e2) {
            int c0 = cbase + e2 * 2, c1 = c0 + 1;
            unsigned short lo, hi;
            if (GATHER) {
                lo = (c0 < 64) ? f2bf(P.W[(size_t)o * 67 + 3 + c0])
                               : (c0 < 67 ? f2bf(P.W[(size_t)o * 67 + c0 - 64]) : (unsigned short)0);
                hi = (c1 < 64) ? f2bf(P.W[(size_t)o * 67 + 3 + c1])
                               : (c1 < 67 ? f2bf(P.W[(size_t)o * 67 + c1 - 64]) : (unsigned short)0);
            } else {
                lo = (c0 < P.cin) ? f2bf(P.W[(size_t)o * P.cin + c0]) : (unsigned short)0;
                hi = (c1 < P.cin) ? f2bf(P.W[(size_t)o * P.cin + c1]) : (unsigned short)0;
            }
            pk[e2] = (unsigned int)lo | ((unsigned int)hi << 16);
        }
        *(uint4*)&Wa[(size_t)s * 8] = make_uint4(pk[0], pk[1], pk[2], pk[3]);
    }
    __syncthreads();

    bf16x8 a[KB][OT];
    #pragma unroll
    for (int kb = 0; kb < KB; ++kb)
        #pragma unroll
        for (int ot = 0; ot < OT; ++ot)
            a[kb][ot] = *(const bf16x8*)&Wa[((kb * OT + ot) * 64 + lane) * 8];

    float sc[KB][8], sh[KB][8];
    if (BN) {
        #pragma unroll
        for (int kb = 0; kb < KB; ++kb)
            #pragma unroll
            for (int e = 0; e < 8; ++e) {
                int c = kb * 32 + q * 8 + e;
                bool ok = c < P.cin;
                sc[kb][e] = ok ? P.ssin[c * 2 + 0] : 0.f;
                sh[kb][e] = ok ? P.ssin[c * 2 + 1] : 0.f;
            }
    }

    float s1_[OT][4], s2_[OT][4], rmax[OT][4];
    #pragma unroll
    for (int ot = 0; ot < OT; ++ot)
        #pragma unroll
        for (int r = 0; r < 4; ++r) { s1_[ot][r] = 0.f; s2_[ot][r] = 0.f; rmax[ot][r] = 0.f; }

    const int wtile0 = (jx * 4 + wid) * TPW;

    // prefetch gather indices + rel coords for all TPW tiles (independent chains)
    int nidxA[TPW];
    ushort4 rlA[TPW];
    if (GATHER) {
        #pragma unroll
        for (int i = 0; i < TPW; ++i) {
            int jj = (wtile0 + i) * 16 + jl;
            nidxA[i] = P.idxb[jj];
            rlA[i] = P.relb[jj];
        }
    }

    #pragma unroll
    for (int i = 0; i < TPW; ++i) {
        const int t = wtile0 + i;
        const int jj = t * 16 + jl;
        f32x4 acc[OT];
        #pragma unroll
        for (int ot = 0; ot < OT; ++ot) acc[ot] = (f32x4){0.f, 0.f, 0.f, 0.f};

        const unsigned short* fr_row = nullptr;
        if (GATHER) {
            int b = jj >> (P.nslog + 10);
            fr_row = P.featsT + (((size_t)b * N_ + nidxA[i]) << 6);
        }

        #pragma unroll
        for (int kb = 0; kb < KB; ++kb) {
            bf16x8 bf;
            if (GATHER) {
                if (kb < 2) {
                    bf = *(const bf16x8*)&fr_row[kb * 32 + q * 8];
                } else {
                    bf = (bf16x8){0, 0, 0, 0, 0, 0, 0, 0};
                    if (q == 0) {
                        bf[0] = (short)rlA[i].x;
                        bf[1] = (short)rlA[i].y;
                        bf[2] = (short)rlA[i].z;
                    }
                }
            } else {
                bf = *(const bf16x8*)&P.Xp[((size_t)(kb * 4 + q) * P.Nj + jj) * 8];
                if (BN) {
                    bf16x8 nb;
                    #pragma unroll
                    for (int e = 0; e < 8; ++e) {
                        float x = bf2f((unsigned short)bf[e]);
                        float z = fmaxf(fmaf(x, sc[kb][e], sh[kb][e]), 0.f);
                        nb[e] = (short)f2bf(z);
                    }
                    bf = nb;
                }
            }
            #pragma unroll
            for (int ot = 0; ot < OT; ++ot)
                acc[ot] = __builtin_amdgcn_mfma_f32_16x16x32_bf16(a[kb][ot], bf, acc[ot], 0, 0, 0);
        }

        #pragma unroll
        for (int ot = 0; ot < OT; ++ot)
            #pragma unroll
            for (int r = 0; r < 4; ++r) {
                float v = acc[ot][r];
                s1_[ot][r] += v;
                s2_[ot][r] = fmaf(v, v, s2_[ot][r]);
            }

        if (!POOL) {
            #pragma unroll
            for (int ot = 0; ot < OT; ++ot) {
                int o0 = oybase + ot * 16 + q * 4;
                unsigned int lo = (unsigned int)f2bf(acc[ot][0]) | ((unsigned int)f2bf(acc[ot][1]) << 16);
                unsigned int hi = (unsigned int)f2bf(acc[ot][2]) | ((unsigned int)f2bf(acc[ot][3]) << 16);
                *(uint2*)&P.Yp[((size_t)(o0 >> 3) * P.Nj + jj) * 8 + (o0 & 7)] = make_uint2(lo, hi);
            }
        } else {
            bool flush = (P.nspool == 16) || ((i & 1) == 1);
            if (flush) {
                float mm[OT][4];
                #pragma unroll
                for (int ot = 0; ot < OT; ++ot)
                    #pragma unroll
                    for (int r = 0; r < 4; ++r)
                        mm[ot][r] = (P.nspool == 32) ? fmaxf(rmax[ot][r], acc[ot][r]) : acc[ot][r];
                #pragma unroll
                for (int ot = 0; ot < OT; ++ot)
                    #pragma unroll
                    for (int r = 0; r < 4; ++r) {
                        float v = mm[ot][r];
                        v = fmaxf(v, __shfl_xor(v, 1));
                        v = fmaxf(v, __shfl_xor(v, 2));
                        v = fmaxf(v, __shfl_xor(v, 4));
                        v = fmaxf(v, __shfl_xor(v, 8));
                        mm[ot][r] = v;
                    }
                if (jl == 0) {
                    int bm = (P.nspool == 32) ? (t >> 1) : t;
                    #pragma unroll
                    for (int ot = 0; ot < OT; ++ot)
                        *(float4*)&P.Ymax[(size_t)bm * 128 + oybase + ot * 16 + q * 4] =
                            make_float4(mm[ot][0], mm[ot][1], mm[ot][2], mm[ot][3]);
                }
            } else {
                #pragma unroll
                for (int ot = 0; ot < OT; ++ot)
                    #pragma unroll
                    for (int r = 0; r < 4; ++r) rmax[ot][r] = acc[ot][r];
            }
        }
    }

    // per-block channel partials
    #pragma unroll
    for (int ot = 0; ot < OT; ++ot)
        #pragma unroll
        for (int r = 0; r < 4; ++r) {
            float v1 = s1_[ot][r], v2 = s2_[ot][r];
            v1 += __shfl_xor(v1, 1); v2 += __shfl_xor(v2, 1);
            v1 += __shfl_xor(v1, 2); v2 += __shfl_xor(v2, 2);
            v1 += __shfl_xor(v1, 4); v2 += __shfl_xor(v2, 4);
            v1 += __shfl_xor(v1, 8); v2 += __shfl_xor(v2, 8);
            s1_[ot][r] = v1; s2_[ot][r] = v2;
        }
    if (jl == 0) {
        #pragma unroll
        for (int ot = 0; ot < OT; ++ot)
            #pragma unroll
            for (int r = 0; r < 4; ++r) {
                sm1[wid][ot * 16 + q * 4 + r] = s1_[ot][r];
                sm2[wid][ot * 16 + q * 4 + r] = s2_[ot][r];
            }
    }
    __syncthreads();
    for (int o = tid; o < OT * 16; o += 256) {
        float a1 = sm1[0][o] + sm1[1][o] + sm1[2][o] + sm1[3][o];
        float a2 = sm2[0][o] + sm2[1][o] + sm2[2][o] + sm2[3][o];
        P.pS[(size_t)(oybase + o) * PST + jx] = a1;
        P.pS2[(size_t)(oybase + o) * PST + jx] = a2;
    }
}

// ------------------------------------------------------------------
// merged fin: blocks [0,ca) scale0 channels, [ca, ...) scale1 channels
__global__ __launch_bounds__(64) void k_fin2(const float* __restrict__ pSa, const float* __restrict__ pS2a,
                                             const float* __restrict__ ga, const float* __restrict__ ba,
                                             float* __restrict__ ssa, int ca, int gxa, float invNa,
                                             const float* __restrict__ pSb, const float* __restrict__ pS2b,
                                             const float* __restrict__ gb, const float* __restrict__ bbv,
                                             float* __restrict__ ssb, int gxb, float invNb) {
    int o = blockIdx.x;
    const float *pS, *pS2, *g, *bt;
    float* ss;
    int gx;
    float invN;
    if (o < ca) { pS = pSa; pS2 = pS2a; g = ga; bt = ba; ss = ssa; gx = gxa; invN = invNa; }
    else { o -= ca; pS = pSb; pS2 = pS2b; g = gb; bt = bbv; ss = ssb; gx = gxb; invN = invNb; }
    int l = threadIdx.x;
    float s = 0.f, s2 = 0.f;
    for (int i = l; i < gx; i += 64) {
        s += pS[(size_t)o * PST + i];
        s2 += pS2[(size_t)o * PST + i];
    }
    #pragma unroll
    for (int off = 1; off < 64; off <<= 1) {
        s += __shfl_xor(s, off, 64);
        s2 += __shfl_xor(s2, off, 64);
    }
    if (l == 0) {
        float mean = s * invN;
        float var = s2 * invN - mean * mean;
        float scale = g[o] / sqrtf(var + 1e-5f);
        float shift = bt[o] - mean * scale;
        ss[o * 2 + 0] = scale;
        ss[o * 2 + 1] = shift;
    }
}

// ------------------------------------------------------------------
// merged poolfin: blocks [0,64) scale0, [64,128) scale1
__global__ __launch_bounds__(256) void k_poolfin2(const float* __restrict__ Ymax0, const float* __restrict__ ss0,
                                                  const float* __restrict__ Ymax1, const float* __restrict__ ss1,
                                                  float* __restrict__ out) {
    __shared__ float T[128][65];
    int blk = blockIdx.x;
    const float* Ymax;
    const float* ss;
    int o_off;
    if (blk < 64) { Ymax = Ymax0; ss = ss0; o_off = 0; }
    else { blk -= 64; Ymax = Ymax1; ss = ss1; o_off = 128; }
    int b = blk >> 4, mc = blk & 15;
    int bm0 = b * M_ + mc * 64;
    for (int s = threadIdx.x; s < 64 * 32; s += 256) {
        int row = s >> 5;
        int c4 = s & 31;
        float4 v = *(const float4*)&Ymax[(size_t)(bm0 + row) * 128 + c4 * 4];
        T[c4 * 4 + 0][row] = v.x;
        T[c4 * 4 + 1][row] = v.y;
        T[c4 * 4 + 2][row] = v.z;
        T[c4 * 4 + 3][row] = v.w;
    }
    __syncthreads();
    for (int s = threadIdx.x; s < 128 * 16; s += 256) {
        int o = s >> 4, m4 = s & 15;
        float scv = ss[o * 2 + 0], shv = ss[o * 2 + 1];
        float4 v = make_float4(T[o][m4 * 4], T[o][m4 * 4 + 1], T[o][m4 * 4 + 2], T[o][m4 * 4 + 3]);
        v.x = fmaxf(fmaf(v.x, scv, shv), 0.f);
        v.y = fmaxf(fmaf(v.y, scv, shv), 0.f);
        v.z = fmaxf(fmaf(v.z, scv, shv), 0.f);
        v.w = fmaxf(fmaf(v.w, scv, shv), 0.f);
        *(float4*)&out[OUT_XYZ_ELEMS + ((size_t)(b * 256 + o_off + o)) * M_ + mc * 64 + m4 * 4] = v;
    }
}

// ------------------------------------------------------------------
extern "C" void kernel_launch(void* const* d_in, const int* in_sizes, int n_in,
                              void* d_out, int out_size, void* d_ws, size_t ws_size,
                              hipStream_t stream) {
    const float* xyz = (const float*)d_in[0];
    const float* feats = (const float*)d_in[1];
    const int* inds = (const int*)d_in[2];
    const float* w[2][3];
    const float* gg[2][3];
    const float* bb[2][3];
    int k = 3;
    for (int i = 0; i < 2; ++i)
        for (int l = 0; l < 3; ++l) {
            w[i][l] = (const float*)d_in[k++];
            gg[i][l] = (const float*)d_in[k++];
            bb[i][l] = (const float*)d_in[k++];
        }
    float* out = (float*)d_out;

    const int Nj0 = B_ * M_ * 16;  // 65536
    const int Nj1 = B_ * M_ * 32;  // 131072

    unsigned short* featsT = (unsigned short*)d_ws;          // B*N*64
    unsigned short* bufB0 = featsT + (size_t)B_ * N_ * 64;   // 8 chunks x Nj0 x 8
    unsigned short* bufA0 = bufB0 + (size_t)8 * Nj0 * 8;     // 12 chunks x Nj0 x 8
    unsigned short* bufB1 = bufA0 + (size_t)12 * Nj0 * 8;    // 8 chunks x Nj1 x 8
    unsigned short* bufA1 = bufB1 + (size_t)8 * Nj1 * 8;     // 12 chunks x Nj1 x 8
    float* Ymax0 = (float*)(bufA1 + (size_t)12 * Nj1 * 8);   // [4096][128]
    float* Ymax1 = Ymax0 + (size_t)B_ * M_ * 128;
    float* pS0 = Ymax1 + (size_t)B_ * M_ * 128;
    float* pS2_0 = pS0 + (size_t)128 * PST;
    float* pS1 = pS2_0 + (size_t)128 * PST;
    float* pS2_1 = pS1 + (size_t)128 * PST;
    float* ss0 = pS2_1 + (size_t)128 * PST;
    float* ss1 = ss0 + 256;
    int* idx0 = (int*)(ss1 + 256);
    int* idx1 = idx0 + Nj0;
    ushort4* rel0 = (ushort4*)(idx1 + Nj1);
    ushort4* rel1 = rel0 + Nj0;

    const float inv0 = 1.f / Nj0, inv1 = 1.f / Nj1;

    // 1) prep: transpose + dual ball + center gather
    k_prep<<<2048, 256, 0, stream>>>(xyz, feats, inds, featsT, out,
                                     idx0, rel0, idx1, rel1,
                                     (float)(0.4 * 0.4), (float)(0.8 * 0.8));

    MMP z{};
    // 2) layer0 merged (GATHER), cout=64 both scales.  TPW=4: 256 cols/block.
    MMP a0 = z, a1 = z;
    a0.W = w[0][0]; a0.Yp = bufB0; a0.pS = pS0; a0.pS2 = pS2_0;
    a0.featsT = featsT; a0.idxb = idx0; a0.relb = rel0;
    a0.cin = 67; a0.Nj = Nj0; a0.nslog = 4; a0.jb_log = 8;
    a1 = a0;
    a1.W = w[1][0]; a1.Yp = bufB1; a1.pS = pS1; a1.pS2 = pS2_1;
    a1.idxb = idx1; a1.relb = rel1; a1.Nj = Nj1; a1.nslog = 5; a1.jb_log = 9;
    k_mm<3, 4, 4, false, true, false><<<768, 256, 0, stream>>>(a0, a1, 256);
    k_fin2<<<128, 64, 0, stream>>>(pS0, pS2_0, gg[0][0], bb[0][0], ss0, 64, 256, inv0,
                                   pS1, pS2_1, gg[1][0], bb[1][0], ss1, 512, inv1);

    // 3) layer1 (separate templates per scale)
    MMP b0 = z;
    b0.W = w[0][1]; b0.Xp = bufB0; b0.ssin = ss0; b0.Yp = bufA0;
    b0.pS = pS0; b0.pS2 = pS2_0; b0.cin = 64; b0.Nj = Nj0; b0.jb_log = 8;
    k_mm<2, 4, 4, true, false, false><<<256, 256, 0, stream>>>(b0, b0, 1 << 30);
    MMP b1 = z;
    b1.W = w[1][1]; b1.Xp = bufB1; b1.ssin = ss1; b1.Yp = bufA1;
    b1.pS = pS1; b1.pS2 = pS2_1; b1.cin = 64; b1.Nj = Nj1; b1.jb_log = 9;
    k_mm<2, 6, 4, true, false, false><<<512, 256, 0, stream>>>(b1, b1, 1 << 30);
    k_fin2<<<160, 64, 0, stream>>>(pS0, pS2_0, gg[0][1], bb[0][1], ss0, 64, 256, inv0,
                                   pS1, pS2_1, gg[1][1], bb[1][1], ss1, 512, inv1);

    // 4) layer2 merged (POOL), cout=128 both scales
    MMP c0 = z, c1 = z;
    c0.W = w[0][2]; c0.Xp = bufA0; c0.ssin = ss0; c0.Ymax = Ymax0;
    c0.pS = pS0; c0.pS2 = pS2_0; c0.cin = 64; c0.Nj = Nj0; c0.nspool = 16; c0.jb_log = 8;
    c1.W = w[1][2]; c1.Xp = bufA1; c1.ssin = ss1; c1.Ymax = Ymax1;
    c1.pS = pS1; c1.pS2 = pS2_1; c1.cin = 96; c1.Nj = Nj1; c1.nspool = 32; c1.jb_log = 9;
    k_mm<3, 4, 4, true, false, true><<<1536, 256, 0, stream>>>(c0, c1, 512);
    k_fin2<<<256, 64, 0, stream>>>(pS0, pS2_0, gg[0][2], bb[0][2], ss0, 128, 256, inv0,
                                   pS1, pS2_1, gg[1][2], bb[1][2], ss1, 512, inv1);

    // 5) final BN+ReLU on pooled maxima + transpose to output
    k_poolfin2<<<128, 256, 0, stream>>>(Ymax0, ss0, Ymax1, ss1, out);
}